// Round 8
// baseline (1718.915 us; speedup 1.0000x reference)
//
#include <hip/hip_runtime.h>
#include <hip/hip_bf16.h>
#include <stdint.h>

typedef __attribute__((ext_vector_type(8))) short short8;
typedef __attribute__((ext_vector_type(4))) float f32x4;

#define B_ 32
#define N_ 196
#define D_ 1024
#define V_ 32000
#define NSTEP 99
#define MROWS 3168   // 99*32
#define NITEMS 3125  // 25 mgroups x 125 ntiles

// workspace layout (bytes)
#define OFF_WT    0ULL          // bf16 [32000][1024]   = 65,536,000
#define OFF_HT    65536000ULL   // u64  [99][16384]     = 12,976,128 (tagged h pairs; no memset needed)
#define OFF_EX    78512128ULL   // u64  [2][16384]      = 262,144 (memset 0)
#define OFF_FSUM  78774272ULL   // f32  [32][1024]
#define OFF_CTX   78905344ULL   // f32  [32][1024]
#define OFF_GBASE 79036416ULL   // f32  [32][4096]
#define OFF_CTL   79560704ULL   // u32 ctl[0]=queue, ctl[1]=convT-done (memset 0)

#define AS3 __attribute__((address_space(3)))
#define AS1 __attribute__((address_space(1)))
static __device__ __forceinline__ void gload_lds16(const void* g, void* l) {
  __builtin_amdgcn_global_load_lds((const AS1 uint32_t*)g, (AS3 uint32_t*)l, 16, 0, 0);
}

// ---------------- fsum[b,e] = sum_n relu(features[b,n,e]) ----------------
__global__ void k_fsum(const float* __restrict__ feat, float* __restrict__ fsum) {
  int idx = blockIdx.x * 256 + threadIdx.x;           // 32768
  int b = idx >> 10, e = idx & 1023;
  const float* p = feat + (size_t)b * (N_ * D_) + e;
  float s = 0.f;
  #pragma unroll 4
  for (int n = 0; n < N_; ++n) s += fmaxf(p[(size_t)n * D_], 0.f);
  fsum[idx] = s;
}

// ---------------- ctx = fsum @ W_fv + 196*b_fv  (16-batch LDS, W_fv read 2x) ----------------
__global__ void k_ctx(const float* __restrict__ fsum, const float* __restrict__ W_fv,
                      const float* __restrict__ b_fv, float* __restrict__ ctx) {
  __shared__ float fs[16][1024];                      // 64 KB
  int b0 = blockIdx.y * 16;                           // grid (16,2)
  int d = blockIdx.x * 64 + (threadIdx.x & 63);
  int bq = threadIdx.x >> 6;                          // 4 batch-quads
  for (int i = threadIdx.x; i < 16384; i += 256)
    fs[i >> 10][i & 1023] = fsum[(b0 + (i >> 10)) * 1024 + (i & 1023)];
  __syncthreads();
  float bias = 196.f * b_fv[d];
  float acc[4] = {bias, bias, bias, bias};
  for (int e4 = 0; e4 < 256; ++e4) {
    float w0 = W_fv[(size_t)(4 * e4 + 0) * 1024 + d];
    float w1 = W_fv[(size_t)(4 * e4 + 1) * 1024 + d];
    float w2 = W_fv[(size_t)(4 * e4 + 2) * 1024 + d];
    float w3 = W_fv[(size_t)(4 * e4 + 3) * 1024 + d];
    #pragma unroll
    for (int r = 0; r < 4; ++r) {
      float4 c = *(const float4*)&fs[bq * 4 + r][e4 * 4];
      acc[r] = fmaf(c.x, w0, fmaf(c.y, w1, fmaf(c.z, w2, fmaf(c.w, w3, acc[r]))));
    }
  }
  #pragma unroll
  for (int r = 0; r < 4; ++r) ctx[(size_t)(b0 + bq * 4 + r) * 1024 + d] = acc[r];
}

// ---------------- gbase = ctx @ W_ih + b_ih + b_hh  (16-batch LDS, W_ih read 2x) ----------------
__global__ void k_gbase(const float* __restrict__ ctx, const float* __restrict__ W_ih,
                        const float* __restrict__ b_ih, const float* __restrict__ b_hh,
                        float* __restrict__ gbase) {
  __shared__ float cs[16][1024];                      // 64 KB
  int b0 = blockIdx.y * 16;                           // grid (16,2)
  int j = blockIdx.x * 256 + threadIdx.x;
  for (int i = threadIdx.x; i < 16384; i += 256)
    cs[i >> 10][i & 1023] = ctx[(size_t)(b0 + (i >> 10)) * 1024 + (i & 1023)];
  __syncthreads();
  float bias = b_ih[j] + b_hh[j];
  float acc[16];
  #pragma unroll
  for (int r = 0; r < 16; ++r) acc[r] = bias;
  for (int e4 = 0; e4 < 256; ++e4) {
    float w0 = W_ih[(size_t)(4 * e4 + 0) * 4096 + j];
    float w1 = W_ih[(size_t)(4 * e4 + 1) * 4096 + j];
    float w2 = W_ih[(size_t)(4 * e4 + 2) * 4096 + j];
    float w3 = W_ih[(size_t)(4 * e4 + 3) * 4096 + j];
    #pragma unroll
    for (int r = 0; r < 16; ++r) {
      float4 c = *(const float4*)&cs[r][e4 * 4];
      acc[r] = fmaf(c.x, w0, fmaf(c.y, w1, fmaf(c.z, w2, fmaf(c.w, w3, acc[r]))));
    }
  }
  #pragma unroll
  for (int r = 0; r < 16; ++r) gbase[(size_t)(b0 + r) * 4096 + j] = acc[r];
}

// ================= mega-kernel: 256 blocks x 256 threads, persistent =================
// blocks 0..127 : LSTM recurrence (round-5 validated) + tagged HT publish; then GEMM consumer
// blocks 128..255: out one-hot; W_lm->WT convT (atomic stores); then GEMM consumer
__global__ __launch_bounds__(256, 1) void k_main(
    const float* __restrict__ gbase, const float* __restrict__ W_hh,
    const float* __restrict__ bos,
    unsigned long long* __restrict__ Ex, unsigned long long* __restrict__ HT,
    const float* __restrict__ W_lm, __hip_bfloat16* __restrict__ WT,
    const float* __restrict__ b_lm, float* __restrict__ out,
    uint32_t* __restrict__ ctl) {
  extern __shared__ char lds[];
  const int tid = threadIdx.x;
  const int blk = blockIdx.x;
  const int lane = tid & 63;
  const int wid = tid >> 6;

  if (blk >= 128) {
    // ============ worker: one-hot + convT ============
    __hip_bfloat16* t = (__hip_bfloat16*)lds;          // [64][66]
    int wblk = blk - 128;
    for (int idx = wblk * 256 + tid; idx < B_ * V_; idx += 128 * 256)
      out[idx] = ((idx % V_) == 0) ? 1.0f : 0.0f;
    int tx = tid & 63, ty = tid >> 6;
    int word = tx & 31, nh = tx >> 5;
    for (int tile = wblk; tile < 8000; tile += 128) {
      int k0 = (tile & 15) * 64;
      int n0 = (tile >> 4) * 64;
      __syncthreads();
      #pragma unroll
      for (int i = 0; i < 16; ++i) {
        int r = i * 4 + ty;
        t[r * 66 + tx] = __float2bfloat16(W_lm[(size_t)(k0 + r) * V_ + n0 + tx]);
      }
      __syncthreads();
      #pragma unroll
      for (int i = 0; i < 8; ++i) {
        int n = i * 8 + ty * 2 + nh;
        uint32_t lo = *(const uint16_t*)&t[2 * word * 66 + n];
        uint32_t hi = *(const uint16_t*)&t[(2 * word + 1) * 66 + n];
        __hip_atomic_store((uint32_t*)&WT[(size_t)(n0 + n) * 1024 + k0] + word,
                           lo | (hi << 16), __ATOMIC_RELAXED, __HIP_MEMORY_SCOPE_AGENT);
      }
    }
    asm volatile("s_waitcnt vmcnt(0)" ::: "memory");   // WT stores acked at coherence point
    if (tid == 0) atomicAdd(&ctl[1], 1u);
  } else {
    // ============ recurrence (round-5 validated; H removed; HT publish added) ============
    __hip_bfloat16* hbuf = (__hip_bfloat16*)lds;             // [32][1024] swizzled
    __hip_bfloat16* wbuf = (__hip_bfloat16*)(lds + 65536);   // init only
    float* gex = (float*)(lds + 131072);                     // [32][33]

    const int d0 = blk * 8;
    for (int idx = tid; idx < 32 * 1024; idx += 256) {
      int c = idx & 31;
      int k = idx >> 5;
      int gcol = ((c >> 3) << 10) + d0 + (c & 7);
      float w = W_hh[(size_t)k * 4096 + gcol];
      wbuf[c * 1024 + ((((k >> 3) ^ (c & 7)) << 3) | (k & 7))] = __float2bfloat16(w);
    }
    for (int idx = tid; idx < 32 * 1024; idx += 256) {
      int row = idx >> 10;
      int k = idx & 1023;
      hbuf[row * 1024 + ((((k >> 3) ^ (row & 7)) << 3) | (k & 7))] = __float2bfloat16(bos[k]);
    }

    const int tb = tid >> 3;
    const int tdl = tid & 7;
    float gb0 = gbase[(size_t)tb * 4096 + 0 * 1024 + d0 + tdl];
    float gb1 = gbase[(size_t)tb * 4096 + 1 * 1024 + d0 + tdl];
    float gb2 = gbase[(size_t)tb * 4096 + 2 * 1024 + d0 + tdl];
    float gb3 = gbase[(size_t)tb * 4096 + 3 * 1024 + d0 + tdl];
    float cst = 0.f;

    const int wm = wid & 1;
    const int wn = wid >> 1;
    const int arow = wm * 16 + (lane & 15);
    const int bcol = wn * 16 + (lane & 15);
    const int kg = lane >> 4;
    const int axor = arow & 7;

    __syncthreads();

    short8 breg[32];
    #pragma unroll
    for (int kt = 0; kt < 32; ++kt) {
      int ca = kt * 4 + kg;
      breg[kt] = *(const short8*)&wbuf[bcol * 1024 + ((ca ^ (bcol & 7)) << 3)];
    }

    const int cbatch = (tid >> 2) & 31;
    const int cpair = tid & 3;
    const int chi = tid >> 7;
    const int cbase = cbatch * 1024 + cpair * 2;
    const int bxor = cbatch & 7;

    for (int t = 0; t < NSTEP; ++t) {
      f32x4 acc0 = {0.f, 0.f, 0.f, 0.f};
      f32x4 acc1 = {0.f, 0.f, 0.f, 0.f};
      #pragma unroll
      for (int kt = 0; kt < 32; kt += 2) {
        int ca = kt * 4 + kg;
        short8 a0 = *(const short8*)&hbuf[arow * 1024 + ((ca ^ axor) << 3)];
        acc0 = __builtin_amdgcn_mfma_f32_16x16x32_bf16(a0, breg[kt], acc0, 0, 0, 0);
        short8 a1 = *(const short8*)&hbuf[arow * 1024 + (((ca + 4) ^ axor) << 3)];
        acc1 = __builtin_amdgcn_mfma_f32_16x16x32_bf16(a1, breg[kt + 1], acc1, 0, 0, 0);
      }
      acc0 = acc0 + acc1;
      {
        int bq = wm * 16 + ((lane >> 4) << 2);
        #pragma unroll
        for (int q = 0; q < 4; ++q) gex[(bq + q) * 33 + bcol] = acc0[q];
      }
      __syncthreads();   // S1

      float gi = gex[tb * 33 + 0  + tdl] + gb0;
      float gf = gex[tb * 33 + 8  + tdl] + gb1;
      float gg = gex[tb * 33 + 16 + tdl] + gb2;
      float go = gex[tb * 33 + 24 + tdl] + gb3;
      float si = 1.f / (1.f + __expf(-gi));
      float sf = 1.f / (1.f + __expf(-gf));
      float so = 1.f / (1.f + __expf(-go));
      cst = sf * cst + si * tanhf(gg);
      float h = so * tanhf(cst);

      float hother = __shfl_xor(h, 1);
      if ((tdl & 1) == 0) {
        __hip_bfloat16 p0 = __float2bfloat16(h);
        __hip_bfloat16 p1 = __float2bfloat16(hother);
        uint32_t pk = (uint32_t)*(uint16_t*)&p0 | ((uint32_t)*(uint16_t*)&p1 << 16);
        unsigned long long v = ((unsigned long long)(unsigned)(t + 1) << 32) | pk;
        // persistent publish for GEMM consumers
        __hip_atomic_store(&HT[(size_t)t * 16384 + tb * 512 + blk * 4 + (tdl >> 1)], v,
                           __ATOMIC_RELAXED, __HIP_MEMORY_SCOPE_AGENT);
        if (t < NSTEP - 1)
          __hip_atomic_store(&Ex[((t & 1) ? 16384 : 0) + blk * 128 + tb * 4 + (tdl >> 1)], v,
                             __ATOMIC_RELAXED, __HIP_MEMORY_SCOPE_AGENT);
      }

      if (t == NSTEP - 1) break;

      {
        const unsigned long long want = (unsigned long long)(unsigned)(t + 1);
        const unsigned long long* ExB = Ex + ((t & 1) ? 16384 : 0);
        for (;;) {
          int nready = 0;
          #pragma unroll
          for (int half = 0; half < 2; ++half) {
            unsigned long long v[32];
            #pragma unroll
            for (int j = 0; j < 32; ++j)
              v[j] = __hip_atomic_load(&ExB[(half * 32 + j) * 256 + tid],
                                       __ATOMIC_RELAXED, __HIP_MEMORY_SCOPE_AGENT);
            #pragma unroll
            for (int j = 0; j < 32; ++j) {
              if ((v[j] >> 32) == want) {
                int slice = (half * 32 + j) * 2 + chi;
                *(uint32_t*)&hbuf[cbase + ((slice ^ bxor) << 3)] = (uint32_t)v[j];
                ++nready;
              }
            }
          }
          if (nready == 64) break;
          __builtin_amdgcn_s_sleep(1);
        }
      }
      __syncthreads();   // S2
    }
    __syncthreads();     // LDS free for GEMM phase
  }

  // ============ GEMM consumer: 128x256 tiles from work queue ============
  {
    __hip_bfloat16* As = (__hip_bfloat16*)lds;             // [2][128*64] = 32 KB
    __hip_bfloat16* Bs = (__hip_bfloat16*)(lds + 32768);   // [2][256*64] = 64 KB
    int* bc = (int*)(lds + 98304);

    if (tid == 0) {  // WT ready?
      while (__hip_atomic_load(&ctl[1], __ATOMIC_RELAXED, __HIP_MEMORY_SCOPE_AGENT) < 128u)
        __builtin_amdgcn_s_sleep(8);
    }
    __syncthreads();

    const int wm = wid & 1;        // M half (64 rows)
    const int wn = wid >> 1;       // N half (128 cols)
    const int kg = lane >> 4;

    // B staging constants (8 chunks/thread)
    int brow[8], bsoff[8];
    #pragma unroll
    for (int j = 0; j < 8; ++j) {
      int c = j * 256 + tid;
      brow[j] = c >> 3;
      bsoff[j] = ((c & 7) ^ (brow[j] & 7)) * 8;
    }
    const int ldsbB = (tid & 192) * 8;

    // A constants (16 tagged words/thread)
    const int r0 = tid >> 1;                 // A-tile row 0..127
    const int ph = tid & 1;
    const int astep = r0 >> 5;               // step within mgroup
    const int abatch = r0 & 31;

    for (;;) {
      if (tid == 0) bc[0] = (int)atomicAdd(&ctl[0], 1u);
      __syncthreads();
      int item = bc[0];
      if (item >= NITEMS) break;
      int g = item / 125;
      int nt = item - g * 125;
      const int mbase = g * 128;
      const int nbase = nt * 256;
      const int gstep = g * 4 + astep;
      const bool avalid = gstep < NSTEP;
      const uint32_t want = (uint32_t)(gstep + 1);
      const unsigned long long* asrc = HT + (size_t)gstep * 16384 + abatch * 512 + ph * 16;

      f32x4 acc[4][8];
      #pragma unroll
      for (int m = 0; m < 4; ++m)
        #pragma unroll
        for (int n = 0; n < 8; ++n) acc[m][n] = (f32x4){0.f, 0.f, 0.f, 0.f};

      unsigned long long av[16];

      auto STAGEB = [&](int nb, int kt) {
        #pragma unroll
        for (int j = 0; j < 8; ++j)
          gload_lds16(WT + (size_t)(nbase + brow[j]) * 1024 + kt * 64 + bsoff[j],
                      Bs + nb * 16384 + j * 2048 + ldsbB);
      };
      auto ALOAD = [&](int kt) {
        if (avalid) {
          #pragma unroll
          for (int i = 0; i < 16; ++i)
            av[i] = __hip_atomic_load(asrc + kt * 32 + i,
                                      __ATOMIC_RELAXED, __HIP_MEMORY_SCOPE_AGENT);
        }
      };
      auto ACOMMIT = [&](int nb, int kt) {
        if (avalid) {
          for (;;) {
            int ok = 1;
            #pragma unroll
            for (int i = 0; i < 16; ++i)
              if ((uint32_t)(av[i] >> 32) != want) {
                av[i] = __hip_atomic_load(asrc + kt * 32 + i,
                                          __ATOMIC_RELAXED, __HIP_MEMORY_SCOPE_AGENT);
                ok = 0;
              }
            if (ok) break;
          }
          #pragma unroll
          for (int i = 0; i < 16; ++i) {
            int e = ph * 32 + 2 * i;
            int off = (((e >> 3) ^ (r0 & 7)) << 3) | (e & 7);
            *(uint32_t*)&As[nb * 8192 + r0 * 64 + off] = (uint32_t)av[i];
          }
        }
      };
      auto COMPUTE = [&](int nb) {
        #pragma unroll
        for (int kk = 0; kk < 2; ++kk) {
          const int slot = kk * 4 + kg;
          short8 a[4], b[8];
          #pragma unroll
          for (int m = 0; m < 4; ++m) {
            int r = wm * 64 + m * 16 + (lane & 15);
            a[m] = *(const short8*)&As[nb * 8192 + r * 64 + ((slot ^ (r & 7)) << 3)];
          }
          #pragma unroll
          for (int n = 0; n < 8; ++n) {
            int r = wn * 128 + n * 16 + (lane & 15);
            b[n] = *(const short8*)&Bs[nb * 16384 + r * 64 + ((slot ^ (r & 7)) << 3)];
          }
          #pragma unroll
          for (int m = 0; m < 4; ++m)
            #pragma unroll
            for (int n = 0; n < 8; ++n)
              acc[m][n] = __builtin_amdgcn_mfma_f32_16x16x32_bf16(a[m], b[n], acc[m][n], 0, 0, 0);
        }
      };

      STAGEB(0, 0);
      ALOAD(0);
      asm volatile("s_waitcnt vmcnt(0) lgkmcnt(0)" ::: "memory");
      ACOMMIT(0, 0);
      __syncthreads();
      for (int kt = 0; kt < 16; ++kt) {
        int cur = kt & 1;
        if (kt < 15) { STAGEB(cur ^ 1, kt + 1); ALOAD(kt + 1); }
        COMPUTE(cur);
        if (kt < 15) {
          asm volatile("s_waitcnt vmcnt(0) lgkmcnt(0)" ::: "memory");
          ACOMMIT(cur ^ 1, kt + 1);
        }
        __syncthreads();
      }

      #pragma unroll
      for (int n = 0; n < 8; ++n) {
        int gcol = nbase + wn * 128 + n * 16 + (lane & 15);
        float bl = b_lm[gcol];
        #pragma unroll
        for (int m = 0; m < 4; ++m) {
          int rb = mbase + wm * 64 + m * 16 + ((lane >> 4) << 2);
          #pragma unroll
          for (int q = 0; q < 4; ++q) {
            int r = rb + q;
            if (r < MROWS)
              out[(size_t)(r + 32) * V_ + gcol] = acc[m][n][q] + bl;
          }
        }
      }
    }
  }
}

extern "C" void kernel_launch(void* const* d_in, const int* in_sizes, int n_in,
                              void* d_out, int out_size, void* d_ws, size_t ws_size,
                              hipStream_t stream) {
  const float* features = (const float*)d_in[0];
  // d_in[1]=W_fk, d_in[2]=b_fk, d_in[5]=W_tk, d_in[6]=b_tk : dead code (softmax over size-1 axis)
  const float* W_fv = (const float*)d_in[3];
  const float* b_fv = (const float*)d_in[4];
  const float* W_ih = (const float*)d_in[7];
  const float* W_hh = (const float*)d_in[8];
  const float* b_ih = (const float*)d_in[9];
  const float* b_hh = (const float*)d_in[10];
  const float* W_lm = (const float*)d_in[11];
  const float* b_lm = (const float*)d_in[12];
  const float* bos  = (const float*)d_in[13];
  float* out = (float*)d_out;
  char* ws = (char*)d_ws;

  __hip_bfloat16* WT     = (__hip_bfloat16*)(ws + OFF_WT);
  unsigned long long* HT = (unsigned long long*)(ws + OFF_HT);
  unsigned long long* Ex = (unsigned long long*)(ws + OFF_EX);
  float* fsum            = (float*)(ws + OFF_FSUM);
  float* ctx             = (float*)(ws + OFF_CTX);
  float* gbase           = (float*)(ws + OFF_GBASE);
  uint32_t* ctl          = (uint32_t*)(ws + OFF_CTL);

  hipLaunchKernelGGL(k_fsum,  dim3(128),    dim3(256), 0, stream, features, fsum);
  hipLaunchKernelGGL(k_ctx,   dim3(16, 2),  dim3(256), 0, stream, fsum, W_fv, b_fv, ctx);
  hipLaunchKernelGGL(k_gbase, dim3(16, 2),  dim3(256), 0, stream, ctx, W_ih, b_ih, b_hh, gbase);
  hipMemsetAsync(Ex, 0, 262144, stream);
  hipMemsetAsync(ctl, 0, 64, stream);
  hipLaunchKernelGGL(k_main,  dim3(256),    dim3(256), 135296, stream,
                     gbase, W_hh, bos, Ex, HT, W_lm, WT, b_lm, out, ctl);
}

// Round 9
// 1286.460 us; speedup vs baseline: 1.3362x; 1.3362x over previous
//
#include <hip/hip_runtime.h>
#include <hip/hip_bf16.h>
#include <stdint.h>

typedef __attribute__((ext_vector_type(8))) short short8;
typedef __attribute__((ext_vector_type(4))) float f32x4;

#define B_ 32
#define N_ 196
#define D_ 1024
#define V_ 32000
#define NSTEP 99
#define MROWS 3168   // 99*32
#define MPAD  3200

// workspace layout (bytes)
#define OFF_WT    0ULL          // bf16 [32000][1024]  = 65,536,000
#define OFF_H     65536000ULL   // bf16 [3200][1024]   =  6,553,600
#define OFF_EX    72089600ULL   // u64  [2][16384]     =    262,144 (memset 0)
#define OFF_FSUM  72351744ULL   // f32  [32][1024]
#define OFF_CTX   72482816ULL   // f32  [32][1024]
#define OFF_GBASE 72613888ULL   // f32  [32][4096]

#define AS3 __attribute__((address_space(3)))
#define AS1 __attribute__((address_space(1)))
static __device__ __forceinline__ void gload_lds16(const void* g, void* l) {
  __builtin_amdgcn_global_load_lds((const AS1 uint32_t*)g, (AS3 uint32_t*)l, 16, 0, 0);
}

// ---------------- fsum[b,e] = sum_n relu(features[b,n,e]) ----------------
__global__ void k_fsum(const float* __restrict__ feat, float* __restrict__ fsum) {
  int idx = blockIdx.x * 256 + threadIdx.x;           // 32768
  int b = idx >> 10, e = idx & 1023;
  const float* p = feat + (size_t)b * (N_ * D_) + e;
  float s = 0.f;
  #pragma unroll 4
  for (int n = 0; n < N_; ++n) s += fmaxf(p[(size_t)n * D_], 0.f);
  fsum[idx] = s;
}

// ---------------- ctx = fsum @ W_fv + 196*b_fv  (16-batch LDS, W_fv read 2x) ----------------
__global__ void k_ctx(const float* __restrict__ fsum, const float* __restrict__ W_fv,
                      const float* __restrict__ b_fv, float* __restrict__ ctx) {
  __shared__ float fs[16][1024];                      // 64 KB
  int b0 = blockIdx.y * 16;                           // grid (16,2)
  int d = blockIdx.x * 64 + (threadIdx.x & 63);
  int bq = threadIdx.x >> 6;                          // 4 batch-quads
  for (int i = threadIdx.x; i < 16384; i += 256)
    fs[i >> 10][i & 1023] = fsum[(b0 + (i >> 10)) * 1024 + (i & 1023)];
  __syncthreads();
  float bias = 196.f * b_fv[d];
  float acc[4] = {bias, bias, bias, bias};
  for (int e4 = 0; e4 < 256; ++e4) {
    float w0 = W_fv[(size_t)(4 * e4 + 0) * 1024 + d];
    float w1 = W_fv[(size_t)(4 * e4 + 1) * 1024 + d];
    float w2 = W_fv[(size_t)(4 * e4 + 2) * 1024 + d];
    float w3 = W_fv[(size_t)(4 * e4 + 3) * 1024 + d];
    #pragma unroll
    for (int r = 0; r < 4; ++r) {
      float4 c = *(const float4*)&fs[bq * 4 + r][e4 * 4];
      acc[r] = fmaf(c.x, w0, fmaf(c.y, w1, fmaf(c.z, w2, fmaf(c.w, w3, acc[r]))));
    }
  }
  #pragma unroll
  for (int r = 0; r < 4; ++r) ctx[(size_t)(b0 + bq * 4 + r) * 1024 + d] = acc[r];
}

// ---------------- gbase = ctx @ W_ih + b_ih + b_hh  (16-batch LDS, W_ih read 2x) ----------------
__global__ void k_gbase(const float* __restrict__ ctx, const float* __restrict__ W_ih,
                        const float* __restrict__ b_ih, const float* __restrict__ b_hh,
                        float* __restrict__ gbase) {
  __shared__ float cs[16][1024];                      // 64 KB
  int b0 = blockIdx.y * 16;                           // grid (16,2)
  int j = blockIdx.x * 256 + threadIdx.x;
  for (int i = threadIdx.x; i < 16384; i += 256)
    cs[i >> 10][i & 1023] = ctx[(size_t)(b0 + (i >> 10)) * 1024 + (i & 1023)];
  __syncthreads();
  float bias = b_ih[j] + b_hh[j];
  float acc[16];
  #pragma unroll
  for (int r = 0; r < 16; ++r) acc[r] = bias;
  for (int e4 = 0; e4 < 256; ++e4) {
    float w0 = W_ih[(size_t)(4 * e4 + 0) * 4096 + j];
    float w1 = W_ih[(size_t)(4 * e4 + 1) * 4096 + j];
    float w2 = W_ih[(size_t)(4 * e4 + 2) * 4096 + j];
    float w3 = W_ih[(size_t)(4 * e4 + 3) * 4096 + j];
    #pragma unroll
    for (int r = 0; r < 16; ++r) {
      float4 c = *(const float4*)&cs[r][e4 * 4];
      acc[r] = fmaf(c.x, w0, fmaf(c.y, w1, fmaf(c.z, w2, fmaf(c.w, w3, acc[r]))));
    }
  }
  #pragma unroll
  for (int r = 0; r < 16; ++r) gbase[(size_t)(b0 + r) * 4096 + j] = acc[r];
}

// ---------------- persistent LSTM recurrence (blocks 0..127) + workers (128..255) ----------------
// Round-7 validated: recurrence = fence-free tagged-u64 exchange; workers do
// out-one-hot, H pad zero, W_lm->WT convT concurrently on the other 128 CUs.
__global__ __launch_bounds__(256, 1) void k_rec(
    const float* __restrict__ gbase, const float* __restrict__ W_hh,
    const float* __restrict__ bos, __hip_bfloat16* __restrict__ H,
    unsigned long long* __restrict__ Ex,
    const float* __restrict__ W_lm, __hip_bfloat16* __restrict__ WT,
    float* __restrict__ out) {
  extern __shared__ char lds[];
  const int tid = threadIdx.x;
  const int blk = blockIdx.x;

  if (blk >= 128) {
    // ---------- worker blocks ----------
    __hip_bfloat16* t = (__hip_bfloat16*)lds;          // [64][66]
    int wblk = blk - 128;
    for (int idx = wblk * 256 + tid; idx < B_ * V_; idx += 128 * 256)
      out[idx] = ((idx % V_) == 0) ? 1.0f : 0.0f;
    if (wblk < 64) ((uint32_t*)(H + (size_t)MROWS * D_))[wblk * 256 + tid] = 0u;
    int tx = tid & 63, ty = tid >> 6;
    int word = tx & 31, nh = tx >> 5;
    for (int tile = wblk; tile < 8000; tile += 128) {
      int k0 = (tile & 15) * 64;
      int n0 = (tile >> 4) * 64;
      __syncthreads();
      #pragma unroll
      for (int i = 0; i < 16; ++i) {
        int r = i * 4 + ty;
        t[r * 66 + tx] = __float2bfloat16(W_lm[(size_t)(k0 + r) * V_ + n0 + tx]);
      }
      __syncthreads();
      #pragma unroll
      for (int i = 0; i < 8; ++i) {
        int n = i * 8 + ty * 2 + nh;
        uint32_t lo = *(const uint16_t*)&t[2 * word * 66 + n];
        uint32_t hi = *(const uint16_t*)&t[(2 * word + 1) * 66 + n];
        ((uint32_t*)&WT[(size_t)(n0 + n) * 1024 + k0])[word] = lo | (hi << 16);
      }
    }
    return;
  }

  // ---------- recurrence blocks (round-5/7 verbatim) ----------
  __hip_bfloat16* hbuf = (__hip_bfloat16*)lds;             // [32][1024] bf16 swizzled (64KB)
  __hip_bfloat16* wbuf = (__hip_bfloat16*)(lds + 65536);   // [32cols][1024] (init only)
  float* gex = (float*)(lds + 131072);                     // [32][33] f32

  const int d0 = blk * 8;

  for (int idx = tid; idx < 32 * 1024; idx += 256) {
    int c = idx & 31;
    int k = idx >> 5;
    int gcol = ((c >> 3) << 10) + d0 + (c & 7);
    float w = W_hh[(size_t)k * 4096 + gcol];
    wbuf[c * 1024 + ((((k >> 3) ^ (c & 7)) << 3) | (k & 7))] = __float2bfloat16(w);
  }
  for (int idx = tid; idx < 32 * 1024; idx += 256) {
    int row = idx >> 10;
    int k = idx & 1023;
    hbuf[row * 1024 + ((((k >> 3) ^ (row & 7)) << 3) | (k & 7))] = __float2bfloat16(bos[k]);
  }

  const int tb = tid >> 3;
  const int tdl = tid & 7;
  float gb0 = gbase[(size_t)tb * 4096 + 0 * 1024 + d0 + tdl];
  float gb1 = gbase[(size_t)tb * 4096 + 1 * 1024 + d0 + tdl];
  float gb2 = gbase[(size_t)tb * 4096 + 2 * 1024 + d0 + tdl];
  float gb3 = gbase[(size_t)tb * 4096 + 3 * 1024 + d0 + tdl];
  float cst = 0.f;

  const int lane = tid & 63;
  const int wid = tid >> 6;
  const int wm = wid & 1;
  const int wn = wid >> 1;
  const int arow = wm * 16 + (lane & 15);
  const int bcol = wn * 16 + (lane & 15);
  const int kg = lane >> 4;
  const int axor = arow & 7;

  __syncthreads();

  short8 breg[32];
  #pragma unroll
  for (int kt = 0; kt < 32; ++kt) {
    int ca = kt * 4 + kg;
    breg[kt] = *(const short8*)&wbuf[bcol * 1024 + ((ca ^ (bcol & 7)) << 3)];
  }

  const int cbatch = (tid >> 2) & 31;
  const int cpair = tid & 3;
  const int chi = tid >> 7;
  const int cbase = cbatch * 1024 + cpair * 2;
  const int bxor = cbatch & 7;

  for (int t = 0; t < NSTEP; ++t) {
    f32x4 acc0 = {0.f, 0.f, 0.f, 0.f};
    f32x4 acc1 = {0.f, 0.f, 0.f, 0.f};
    #pragma unroll
    for (int kt = 0; kt < 32; kt += 2) {
      int ca = kt * 4 + kg;
      short8 a0 = *(const short8*)&hbuf[arow * 1024 + ((ca ^ axor) << 3)];
      acc0 = __builtin_amdgcn_mfma_f32_16x16x32_bf16(a0, breg[kt], acc0, 0, 0, 0);
      short8 a1 = *(const short8*)&hbuf[arow * 1024 + (((ca + 4) ^ axor) << 3)];
      acc1 = __builtin_amdgcn_mfma_f32_16x16x32_bf16(a1, breg[kt + 1], acc1, 0, 0, 0);
    }
    acc0 = acc0 + acc1;
    {
      int bq = wm * 16 + ((lane >> 4) << 2);
      #pragma unroll
      for (int q = 0; q < 4; ++q) gex[(bq + q) * 33 + bcol] = acc0[q];
    }
    __syncthreads();   // S1

    float gi = gex[tb * 33 + 0  + tdl] + gb0;
    float gf = gex[tb * 33 + 8  + tdl] + gb1;
    float gg = gex[tb * 33 + 16 + tdl] + gb2;
    float go = gex[tb * 33 + 24 + tdl] + gb3;
    float si = 1.f / (1.f + __expf(-gi));
    float sf = 1.f / (1.f + __expf(-gf));
    float so = 1.f / (1.f + __expf(-go));
    cst = sf * cst + si * tanhf(gg);
    float h = so * tanhf(cst);
    H[(size_t)t * (B_ * D_) + tb * D_ + d0 + tdl] = __float2bfloat16(h);

    float hother = __shfl_xor(h, 1);
    if ((tdl & 1) == 0) {
      __hip_bfloat16 p0 = __float2bfloat16(h);
      __hip_bfloat16 p1 = __float2bfloat16(hother);
      uint32_t pk = (uint32_t)*(uint16_t*)&p0 | ((uint32_t)*(uint16_t*)&p1 << 16);
      unsigned long long v = ((unsigned long long)(unsigned)(t + 1) << 32) | pk;
      unsigned long long* dst = Ex + ((t & 1) ? 16384 : 0) + blk * 128 + tb * 4 + (tdl >> 1);
      __hip_atomic_store(dst, v, __ATOMIC_RELAXED, __HIP_MEMORY_SCOPE_AGENT);
    }

    if (t == NSTEP - 1) break;

    {
      const unsigned long long want = (unsigned long long)(unsigned)(t + 1);
      const unsigned long long* ExB = Ex + ((t & 1) ? 16384 : 0);
      for (;;) {
        int nready = 0;
        #pragma unroll
        for (int half = 0; half < 2; ++half) {
          unsigned long long v[32];
          #pragma unroll
          for (int j = 0; j < 32; ++j)
            v[j] = __hip_atomic_load(&ExB[(half * 32 + j) * 256 + tid],
                                     __ATOMIC_RELAXED, __HIP_MEMORY_SCOPE_AGENT);
          #pragma unroll
          for (int j = 0; j < 32; ++j) {
            if ((v[j] >> 32) == want) {
              int slice = (half * 32 + j) * 2 + chi;
              *(uint32_t*)&hbuf[cbase + ((slice ^ bxor) << 3)] = (uint32_t)v[j];
              ++nready;
            }
          }
        }
        if (nready == 64) break;
        __builtin_amdgcn_s_sleep(1);
      }
    }
    __syncthreads();   // S2
  }
}

// ---------------- logits GEMM: 128x256 tiles, TRIPLE-buffered depth-2 pipeline ----------------
// Loads for tile kt issued at kt-2 (two compute phases of latency cover). Counted
// vmcnt(12/6/0), never drained mid-loop; setprio around MFMA cluster (T3/T4/T5).
__global__ __launch_bounds__(512, 1) void k_gemm(
    const __hip_bfloat16* __restrict__ H,    // [3200][1024] (rows 3168..3199 zero)
    const __hip_bfloat16* __restrict__ WT,   // [32000][1024]
    const float* __restrict__ b_lm,
    float* __restrict__ out) {
  extern __shared__ char glds[];
  __hip_bfloat16* As = (__hip_bfloat16*)glds;            // [3][128*64] = 48 KB
  __hip_bfloat16* Bs = (__hip_bfloat16*)(glds + 49152);  // [3][256*64] = 96 KB

  // XCD-bijective remap: nwg = 3125 = 8*390 + 5
  int bid = blockIdx.x;
  int xcd = bid & 7;
  int idx = bid >> 3;
  int wg = (xcd < 5 ? xcd * 391 : 5 * 391 + (xcd - 5) * 390) + idx;
  // grouped raster: 5 groups x (5 mt x 125 nt), mt fastest -> B panel reused 5x in-XCD
  int g = wg / 625;
  int u = wg - g * 625;
  int mt = g * 5 + (u % 5);                 // 0..24
  int nt = u / 5;                           // 0..124
  const int mbase = mt * 128;
  const int nbase = nt * 256;

  const int tid = threadIdx.x;
  const int lane = tid & 63;
  const int wid = tid >> 6;      // 0..7
  const int wm = wid >> 2;       // 0..1  (M 64-half)
  const int wn = wid & 3;        // 0..3  (N 64-quarter)
  const int kg = lane >> 4;

  f32x4 acc[4][4];
  #pragma unroll
  for (int m = 0; m < 4; ++m)
    #pragma unroll
    for (int n = 0; n < 4; ++n) acc[m][n] = (f32x4){0.f, 0.f, 0.f, 0.f};

  // staging constants (A: 2 chunks/thread, B: 4 chunks/thread)
  int arw[2], aso[2];
  #pragma unroll
  for (int j = 0; j < 2; ++j) {
    int c = j * 512 + tid;
    int r = c >> 3;
    arw[j] = mbase + r;                      // 0..3199 (last tile row max = 3199)
    aso[j] = ((c & 7) ^ (r & 7)) * 8;
  }
  int brw[4], bso[4];
  #pragma unroll
  for (int j = 0; j < 4; ++j) {
    int c = j * 512 + tid;
    int r = c >> 3;
    brw[j] = nbase + r;
    bso[j] = ((c & 7) ^ (r & 7)) * 8;
  }
  const int ldsb = (tid & 448) * 8;          // wave-uniform elem base

  auto STAGE = [&](int s, int kt) {
    #pragma unroll
    for (int j = 0; j < 2; ++j)
      gload_lds16(H + (size_t)arw[j] * 1024 + kt * 64 + aso[j],
                  As + s * 8192 + j * 4096 + ldsb);
    #pragma unroll
    for (int j = 0; j < 4; ++j)
      gload_lds16(WT + (size_t)brw[j] * 1024 + kt * 64 + bso[j],
                  Bs + s * 16384 + j * 4096 + ldsb);
  };
  auto COMPUTE = [&](int s) {
    #pragma unroll
    for (int kk = 0; kk < 2; ++kk) {
      const int slot = kk * 4 + kg;
      short8 a[4], b[4];
      #pragma unroll
      for (int m = 0; m < 4; ++m) {
        int r = wm * 64 + m * 16 + (lane & 15);
        a[m] = *(const short8*)&As[s * 8192 + r * 64 + ((slot ^ (r & 7)) << 3)];
      }
      #pragma unroll
      for (int n = 0; n < 4; ++n) {
        int r = wn * 64 + n * 16 + (lane & 15);
        b[n] = *(const short8*)&Bs[s * 16384 + r * 64 + ((slot ^ (r & 7)) << 3)];
      }
      #pragma unroll
      for (int m = 0; m < 4; ++m)
        #pragma unroll
        for (int n = 0; n < 4; ++n)
          acc[m][n] = __builtin_amdgcn_mfma_f32_16x16x32_bf16(a[m], b[n], acc[m][n], 0, 0, 0);
    }
  };

  STAGE(0, 0);
  STAGE(1, 1);
  for (int kt = 0; kt < 16; ++kt) {
    int s = kt % 3;
    if (kt < 14) {
      STAGE((kt + 2) % 3, kt + 2);                      // depth-2 prefetch
      asm volatile("s_waitcnt vmcnt(12)" ::: "memory"); // tile kt's 6 loads done
    } else if (kt == 14) {
      asm volatile("s_waitcnt vmcnt(6)" ::: "memory");
    } else {
      asm volatile("s_waitcnt vmcnt(0)" ::: "memory");
    }
    __builtin_amdgcn_s_barrier();
    __builtin_amdgcn_sched_barrier(0);
    __builtin_amdgcn_s_setprio(1);
    COMPUTE(s);
    __builtin_amdgcn_s_setprio(0);
    __builtin_amdgcn_sched_barrier(0);
    __builtin_amdgcn_s_barrier();                       // reads done before re-stage
  }

  #pragma unroll
  for (int n = 0; n < 4; ++n) {
    int gcol = nbase + wn * 64 + n * 16 + (lane & 15);
    float bl = b_lm[gcol];
    #pragma unroll
    for (int m = 0; m < 4; ++m) {
      int rb = mbase + wm * 64 + m * 16 + ((lane >> 4) << 2);
      #pragma unroll
      for (int q = 0; q < 4; ++q) {
        int r = rb + q;
        if (r < MROWS)
          out[(size_t)(r + 32) * V_ + gcol] = acc[m][n][q] + bl;
      }
    }
  }
}

extern "C" void kernel_launch(void* const* d_in, const int* in_sizes, int n_in,
                              void* d_out, int out_size, void* d_ws, size_t ws_size,
                              hipStream_t stream) {
  const float* features = (const float*)d_in[0];
  // d_in[1]=W_fk, d_in[2]=b_fk, d_in[5]=W_tk, d_in[6]=b_tk : dead code (softmax over size-1 axis)
  const float* W_fv = (const float*)d_in[3];
  const float* b_fv = (const float*)d_in[4];
  const float* W_ih = (const float*)d_in[7];
  const float* W_hh = (const float*)d_in[8];
  const float* b_ih = (const float*)d_in[9];
  const float* b_hh = (const float*)d_in[10];
  const float* W_lm = (const float*)d_in[11];
  const float* b_lm = (const float*)d_in[12];
  const float* bos  = (const float*)d_in[13];
  float* out = (float*)d_out;
  char* ws = (char*)d_ws;

  __hip_bfloat16* WT   = (__hip_bfloat16*)(ws + OFF_WT);
  __hip_bfloat16* H    = (__hip_bfloat16*)(ws + OFF_H);
  unsigned long long* Ex = (unsigned long long*)(ws + OFF_EX);
  float* fsum          = (float*)(ws + OFF_FSUM);
  float* ctx           = (float*)(ws + OFF_CTX);
  float* gbase         = (float*)(ws + OFF_GBASE);

  hipLaunchKernelGGL(k_fsum,  dim3(128),    dim3(256), 0, stream, features, fsum);
  hipLaunchKernelGGL(k_ctx,   dim3(16, 2),  dim3(256), 0, stream, fsum, W_fv, b_fv, ctx);
  hipLaunchKernelGGL(k_gbase, dim3(16, 2),  dim3(256), 0, stream, ctx, W_ih, b_ih, b_hh, gbase);
  hipMemsetAsync(Ex, 0, 262144, stream);
  // blocks 0..127: recurrence; 128..255: one-hot + H pad + W_lm->WT (concurrent)
  hipLaunchKernelGGL(k_rec,   dim3(256),  dim3(256), 135296, stream,
                     gbase, W_hh, bos, H, Ex, W_lm, WT, out);
  hipLaunchKernelGGL(k_gemm,  dim3(3125), dim3(512), 147456, stream, H, WT, b_lm, out);
}

// Round 10
// 1155.858 us; speedup vs baseline: 1.4871x; 1.1130x over previous
//
#include <hip/hip_runtime.h>
#include <hip/hip_bf16.h>
#include <stdint.h>

typedef __attribute__((ext_vector_type(8))) short short8;
typedef __attribute__((ext_vector_type(4))) float f32x4;

#define B_ 32
#define N_ 196
#define D_ 1024
#define V_ 32000
#define NSTEP 99
#define MROWS 3168   // 99*32
#define MPAD  3200
#define SENT  0x7FC07FC07FC07FC0ULL   // 4x bf16 NaN: unreachable as packed h (|h|<1)

// workspace layout (bytes)
#define OFF_WT    0ULL          // bf16 [32000][1024]  = 65,536,000
#define OFF_H     65536000ULL   // bf16 [3200][1024]   =  6,553,600  (u64 view: [99][8192] + pad rows)
#define OFF_FSUM  72089600ULL   // f32  [32][1024]
#define OFF_CTX   72220672ULL   // f32  [32][1024]
#define OFF_GBASE 72351744ULL   // f32  [32][4096]

#define AS3 __attribute__((address_space(3)))
#define AS1 __attribute__((address_space(1)))
static __device__ __forceinline__ void gload_lds16(const void* g, void* l) {
  __builtin_amdgcn_global_load_lds((const AS1 uint32_t*)g, (AS3 uint32_t*)l, 16, 0, 0);
}

// ---------------- sentinel-fill H[0..99) steps (u64 view) ----------------
__global__ void k_init(unsigned long long* __restrict__ Hq) {
  int base = (blockIdx.x * 256 + threadIdx.x) * 4;   // grid 792 -> 811,008 words
  #pragma unroll
  for (int j = 0; j < 4; ++j) Hq[base + j] = SENT;
}

// ---------------- fsum[b,e] = sum_n relu(features[b,n,e]) ----------------
__global__ void k_fsum(const float* __restrict__ feat, float* __restrict__ fsum) {
  int idx = blockIdx.x * 256 + threadIdx.x;           // 32768
  int b = idx >> 10, e = idx & 1023;
  const float* p = feat + (size_t)b * (N_ * D_) + e;
  float s = 0.f;
  #pragma unroll 4
  for (int n = 0; n < N_; ++n) s += fmaxf(p[(size_t)n * D_], 0.f);
  fsum[idx] = s;
}

// ---------------- ctx = fsum @ W_fv + 196*b_fv  (16-batch LDS, W_fv read 2x) ----------------
__global__ void k_ctx(const float* __restrict__ fsum, const float* __restrict__ W_fv,
                      const float* __restrict__ b_fv, float* __restrict__ ctx) {
  __shared__ float fs[16][1024];                      // 64 KB
  int b0 = blockIdx.y * 16;                           // grid (16,2)
  int d = blockIdx.x * 64 + (threadIdx.x & 63);
  int bq = threadIdx.x >> 6;                          // 4 batch-quads
  for (int i = threadIdx.x; i < 16384; i += 256)
    fs[i >> 10][i & 1023] = fsum[(b0 + (i >> 10)) * 1024 + (i & 1023)];
  __syncthreads();
  float bias = 196.f * b_fv[d];
  float acc[4] = {bias, bias, bias, bias};
  for (int e4 = 0; e4 < 256; ++e4) {
    float w0 = W_fv[(size_t)(4 * e4 + 0) * 1024 + d];
    float w1 = W_fv[(size_t)(4 * e4 + 1) * 1024 + d];
    float w2 = W_fv[(size_t)(4 * e4 + 2) * 1024 + d];
    float w3 = W_fv[(size_t)(4 * e4 + 3) * 1024 + d];
    #pragma unroll
    for (int r = 0; r < 4; ++r) {
      float4 c = *(const float4*)&fs[bq * 4 + r][e4 * 4];
      acc[r] = fmaf(c.x, w0, fmaf(c.y, w1, fmaf(c.z, w2, fmaf(c.w, w3, acc[r]))));
    }
  }
  #pragma unroll
  for (int r = 0; r < 4; ++r) ctx[(size_t)(b0 + bq * 4 + r) * 1024 + d] = acc[r];
}

// ---------------- gbase = ctx @ W_ih + b_ih + b_hh  (16-batch LDS, W_ih read 2x) ----------------
__global__ void k_gbase(const float* __restrict__ ctx, const float* __restrict__ W_ih,
                        const float* __restrict__ b_ih, const float* __restrict__ b_hh,
                        float* __restrict__ gbase) {
  __shared__ float cs[16][1024];                      // 64 KB
  int b0 = blockIdx.y * 16;                           // grid (16,2)
  int j = blockIdx.x * 256 + threadIdx.x;
  for (int i = threadIdx.x; i < 16384; i += 256)
    cs[i >> 10][i & 1023] = ctx[(size_t)(b0 + (i >> 10)) * 1024 + (i & 1023)];
  __syncthreads();
  float bias = b_ih[j] + b_hh[j];
  float acc[16];
  #pragma unroll
  for (int r = 0; r < 16; ++r) acc[r] = bias;
  for (int e4 = 0; e4 < 256; ++e4) {
    float w0 = W_ih[(size_t)(4 * e4 + 0) * 4096 + j];
    float w1 = W_ih[(size_t)(4 * e4 + 1) * 4096 + j];
    float w2 = W_ih[(size_t)(4 * e4 + 2) * 4096 + j];
    float w3 = W_ih[(size_t)(4 * e4 + 3) * 4096 + j];
    #pragma unroll
    for (int r = 0; r < 16; ++r) {
      float4 c = *(const float4*)&cs[r][e4 * 4];
      acc[r] = fmaf(c.x, w0, fmaf(c.y, w1, fmaf(c.z, w2, fmaf(c.w, w3, acc[r]))));
    }
  }
  #pragma unroll
  for (int r = 0; r < 16; ++r) gbase[(size_t)(b0 + r) * 4096 + j] = acc[r];
}

// ---------------- persistent LSTM recurrence (blocks 0..127) + workers (128..255) ----------------
// Sentinel-payload exchange: h published as packed 4xbf16 u64 agent atomics directly into
// H[t] (row-major; never overwritten). Consumers poll H[t] words until != SENT. No tags,
// no parity buffer. Workers: out one-hot, H pad zero, W_lm->WT convT (concurrent).
__global__ __launch_bounds__(256, 1) void k_rec(
    const float* __restrict__ gbase, const float* __restrict__ W_hh,
    const float* __restrict__ bos, unsigned long long* __restrict__ Hq,
    const float* __restrict__ W_lm, __hip_bfloat16* __restrict__ WT,
    float* __restrict__ out) {
  extern __shared__ char lds[];
  const int tid = threadIdx.x;
  const int blk = blockIdx.x;

  if (blk >= 128) {
    // ---------- worker blocks ----------
    __hip_bfloat16* t = (__hip_bfloat16*)lds;          // [64][66]
    int wblk = blk - 128;
    for (int idx = wblk * 256 + tid; idx < B_ * V_; idx += 128 * 256)
      out[idx] = ((idx % V_) == 0) ? 1.0f : 0.0f;
    if (wblk < 64) ((uint32_t*)(Hq + (size_t)MROWS * 128))[wblk * 256 + tid] = 0u;  // pad rows
    int tx = tid & 63, ty = tid >> 6;
    int word = tx & 31, nh = tx >> 5;
    for (int tile = wblk; tile < 8000; tile += 128) {
      int k0 = (tile & 15) * 64;
      int n0 = (tile >> 4) * 64;
      __syncthreads();
      #pragma unroll
      for (int i = 0; i < 16; ++i) {
        int r = i * 4 + ty;
        t[r * 66 + tx] = __float2bfloat16(W_lm[(size_t)(k0 + r) * V_ + n0 + tx]);
      }
      __syncthreads();
      #pragma unroll
      for (int i = 0; i < 8; ++i) {
        int n = i * 8 + ty * 2 + nh;
        uint32_t lo = *(const uint16_t*)&t[2 * word * 66 + n];
        uint32_t hi = *(const uint16_t*)&t[(2 * word + 1) * 66 + n];
        ((uint32_t*)&WT[(size_t)(n0 + n) * 1024 + k0])[word] = lo | (hi << 16);
      }
    }
    return;
  }

  // ---------- recurrence blocks ----------
  __hip_bfloat16* hbuf = (__hip_bfloat16*)lds;             // [32][1024] bf16 swizzled (64KB)
  __hip_bfloat16* wbuf = (__hip_bfloat16*)(lds + 65536);   // [32cols][1024] (init only)
  float* gex = (float*)(lds + 131072);                     // [32][33] f32

  const int d0 = blk * 8;

  for (int idx = tid; idx < 32 * 1024; idx += 256) {
    int c = idx & 31;
    int k = idx >> 5;
    int gcol = ((c >> 3) << 10) + d0 + (c & 7);
    float w = W_hh[(size_t)k * 4096 + gcol];
    wbuf[c * 1024 + ((((k >> 3) ^ (c & 7)) << 3) | (k & 7))] = __float2bfloat16(w);
  }
  for (int idx = tid; idx < 32 * 1024; idx += 256) {
    int row = idx >> 10;
    int k = idx & 1023;
    hbuf[row * 1024 + ((((k >> 3) ^ (row & 7)) << 3) | (k & 7))] = __float2bfloat16(bos[k]);
  }

  const int tb = tid >> 3;     // batch 0..31
  const int tdl = tid & 7;     // local dim 0..7
  float gb0 = gbase[(size_t)tb * 4096 + 0 * 1024 + d0 + tdl];
  float gb1 = gbase[(size_t)tb * 4096 + 1 * 1024 + d0 + tdl];
  float gb2 = gbase[(size_t)tb * 4096 + 2 * 1024 + d0 + tdl];
  float gb3 = gbase[(size_t)tb * 4096 + 3 * 1024 + d0 + tdl];
  float cst = 0.f;

  const int lane = tid & 63;
  const int wid = tid >> 6;
  const int wm = wid & 1;
  const int wn = wid >> 1;
  const int arow = wm * 16 + (lane & 15);
  const int bcol = wn * 16 + (lane & 15);
  const int kg = lane >> 4;
  const int axor = arow & 7;

  __syncthreads();

  short8 breg[32];
  #pragma unroll
  for (int kt = 0; kt < 32; ++kt) {
    int ca = kt * 4 + kg;
    breg[kt] = *(const short8*)&wbuf[bcol * 1024 + ((ca ^ (bcol & 7)) << 3)];
  }

  // publish constants: lanes tdl%4==0 store word q = d>>2 of row tb
  const unsigned long long* HqC = Hq;            // consumer view
  const int pubw = tb * 256 + blk * 2 + (tdl >> 2);
  // consumer: thread handles words w = j*256 + tid (j=0..31): row=j, d=4*tid
  const int coffA = (((tid >> 1) ^ 0) << 3);     // recomputed per j below (xor depends on j)

  for (int t = 0; t < NSTEP; ++t) {
    f32x4 acc0 = {0.f, 0.f, 0.f, 0.f};
    f32x4 acc1 = {0.f, 0.f, 0.f, 0.f};
    #pragma unroll
    for (int kt = 0; kt < 32; kt += 2) {
      int ca = kt * 4 + kg;
      short8 a0 = *(const short8*)&hbuf[arow * 1024 + ((ca ^ axor) << 3)];
      acc0 = __builtin_amdgcn_mfma_f32_16x16x32_bf16(a0, breg[kt], acc0, 0, 0, 0);
      short8 a1 = *(const short8*)&hbuf[arow * 1024 + (((ca + 4) ^ axor) << 3)];
      acc1 = __builtin_amdgcn_mfma_f32_16x16x32_bf16(a1, breg[kt + 1], acc1, 0, 0, 0);
    }
    acc0 = acc0 + acc1;
    {
      int bq = wm * 16 + ((lane >> 4) << 2);
      #pragma unroll
      for (int q = 0; q < 4; ++q) gex[(bq + q) * 33 + bcol] = acc0[q];
    }
    __syncthreads();   // S1

    float gi = gex[tb * 33 + 0  + tdl] + gb0;
    float gf = gex[tb * 33 + 8  + tdl] + gb1;
    float gg = gex[tb * 33 + 16 + tdl] + gb2;
    float go = gex[tb * 33 + 24 + tdl] + gb3;
    float si = 1.f / (1.f + __expf(-gi));
    float sf = 1.f / (1.f + __expf(-gf));
    float so = 1.f / (1.f + __expf(-go));
    cst = sf * cst + si * tanhf(gg);
    float h = so * tanhf(cst);

    // publish packed 4x bf16 (sentinel-free payload) straight into H[t]
    float h1 = __shfl_down(h, 1);
    float h2 = __shfl_down(h, 2);
    float h3 = __shfl_down(h, 3);
    if ((tdl & 3) == 0) {
      __hip_bfloat16 q0 = __float2bfloat16(h), q1 = __float2bfloat16(h1);
      __hip_bfloat16 q2 = __float2bfloat16(h2), q3 = __float2bfloat16(h3);
      unsigned long long v = (unsigned long long)*(uint16_t*)&q0
                           | ((unsigned long long)*(uint16_t*)&q1 << 16)
                           | ((unsigned long long)*(uint16_t*)&q2 << 32)
                           | ((unsigned long long)*(uint16_t*)&q3 << 48);
      __hip_atomic_store(&Hq[(size_t)t * 8192 + pubw], v,
                         __ATOMIC_RELAXED, __HIP_MEMORY_SCOPE_AGENT);
    }

    if (t == NSTEP - 1) break;

    // poll H[t]: 32 words/thread (64 KB/block), deposit into hbuf as they arrive
    {
      const unsigned long long* src = HqC + (size_t)t * 8192;
      for (;;) {
        int nready = 0;
        #pragma unroll
        for (int half = 0; half < 2; ++half) {
          unsigned long long v[16];
          #pragma unroll
          for (int j = 0; j < 16; ++j)
            v[j] = __hip_atomic_load(&src[(half * 16 + j) * 256 + tid],
                                     __ATOMIC_RELAXED, __HIP_MEMORY_SCOPE_AGENT);
          #pragma unroll
          for (int j = 0; j < 16; ++j) {
            if (v[j] != SENT) {
              int row = half * 16 + j;                 // batch
              int off = (((tid >> 1) ^ (row & 7)) << 3) + ((tid & 1) << 2);
              *(uint2*)&hbuf[row * 1024 + off] = *(uint2*)&v[j];
              ++nready;
            }
          }
        }
        if (nready == 32) break;
        __builtin_amdgcn_s_sleep(1);
      }
    }
    __syncthreads();   // S2
  }
}

// ---------------- logits GEMM (round-7 validated): 256x256, 2-stage dbuf, vmcnt(8) ----------------
__global__ __launch_bounds__(512, 1) void k_gemm(
    const __hip_bfloat16* __restrict__ H,    // [3200][1024] (rows 3168..3199 zero)
    const __hip_bfloat16* __restrict__ WT,   // [32000][1024]
    const float* __restrict__ b_lm,
    float* __restrict__ out) {
  extern __shared__ char glds[];
  __hip_bfloat16* As = (__hip_bfloat16*)glds;            // [2][256*64] = 64 KB
  __hip_bfloat16* Bs = (__hip_bfloat16*)(glds + 65536);  // [2][256*64] = 64 KB

  // XCD-bijective remap: nwg = 1625 = 8*203 + 1
  int bid = blockIdx.x;
  int xcd = bid & 7;
  int idx = bid >> 3;
  int wg = (xcd < 1 ? xcd * 204 : 204 + (xcd - 1) * 203) + idx;
  // grouped raster: groups of GM=4 m-tiles, mt fastest within group (13 = 4+4+4+1)
  int group = wg / 500;                       // 0..3
  int u = wg - group * 500;
  int gm = (group == 3) ? 1 : 4;
  int mt = group * 4 + (u % gm);              // 0..12
  int nt = u / gm;                            // 0..124
  const int mbase = mt * 256;
  const int nbase = nt * 256;

  const int tid = threadIdx.x;
  const int lane = tid & 63;
  const int wid = tid >> 6;      // 0..7
  const int wm = wid >> 2;       // 0..1  (M 128-half)
  const int wn = wid & 3;        // 0..3  (N 64-quarter)

  f32x4 acc[8][4];
  #pragma unroll
  for (int m = 0; m < 8; ++m)
    #pragma unroll
    for (int n = 0; n < 4; ++n) acc[m][n] = (f32x4){0.f, 0.f, 0.f, 0.f};

  const int kg = lane >> 4;

  int srowA[4], srowB[4], soff[4];
  #pragma unroll
  for (int j = 0; j < 4; ++j) {
    int c = j * 512 + tid;
    int row = c >> 3;
    srowB[j] = nbase + row;
    srowA[j] = min(mbase + row, MPAD - 1);   // clamp pad rows (zeros)
    soff[j] = ((c & 7) ^ (row & 7)) * 8;
  }
  const int ldsbase = (tid & 448) * 8;

  auto STAGE = [&](int nb, int kt) {
    #pragma unroll
    for (int j = 0; j < 4; ++j)
      gload_lds16(H + (size_t)srowA[j] * 1024 + kt * 64 + soff[j],
                  As + nb * 16384 + j * 4096 + ldsbase);
    #pragma unroll
    for (int j = 0; j < 4; ++j)
      gload_lds16(WT + (size_t)srowB[j] * 1024 + kt * 64 + soff[j],
                  Bs + nb * 16384 + j * 4096 + ldsbase);
  };
  auto COMPUTE = [&](int nb) {
    #pragma unroll
    for (int kk = 0; kk < 2; ++kk) {
      const int slot = kk * 4 + kg;
      short8 a[8], b[4];
      #pragma unroll
      for (int m = 0; m < 8; ++m) {
        int r = wm * 128 + m * 16 + (lane & 15);
        a[m] = *(const short8*)&As[nb * 16384 + r * 64 + ((slot ^ (r & 7)) << 3)];
      }
      #pragma unroll
      for (int n = 0; n < 4; ++n) {
        int r = wn * 64 + n * 16 + (lane & 15);
        b[n] = *(const short8*)&Bs[nb * 16384 + r * 64 + ((slot ^ (r & 7)) << 3)];
      }
      #pragma unroll
      for (int m = 0; m < 8; ++m)
        #pragma unroll
        for (int n = 0; n < 4; ++n)
          acc[m][n] = __builtin_amdgcn_mfma_f32_16x16x32_bf16(a[m], b[n], acc[m][n], 0, 0, 0);
    }
  };

  STAGE(0, 0);
  for (int kt = 0; kt < 15; ++kt) {
    STAGE((kt + 1) & 1, kt + 1);
    asm volatile("s_waitcnt vmcnt(8)" ::: "memory");
    __builtin_amdgcn_s_barrier();
    __builtin_amdgcn_sched_barrier(0);
    COMPUTE(kt & 1);
    __builtin_amdgcn_sched_barrier(0);
    __builtin_amdgcn_s_barrier();
  }
  asm volatile("s_waitcnt vmcnt(0)" ::: "memory");
  __builtin_amdgcn_s_barrier();
  __builtin_amdgcn_sched_barrier(0);
  COMPUTE(1);

  #pragma unroll
  for (int n = 0; n < 4; ++n) {
    int gcol = nbase + wn * 64 + n * 16 + (lane & 15);
    float bl = b_lm[gcol];
    #pragma unroll
    for (int m = 0; m < 8; ++m) {
      int rbase = mbase + wm * 128 + m * 16 + ((lane >> 4) << 2);
      #pragma unroll
      for (int q = 0; q < 4; ++q) {
        int r = rbase + q;
        if (r < MROWS)
          out[(size_t)(r + 32) * V_ + gcol] = acc[m][n][q] + bl;
      }
    }
  }
}

extern "C" void kernel_launch(void* const* d_in, const int* in_sizes, int n_in,
                              void* d_out, int out_size, void* d_ws, size_t ws_size,
                              hipStream_t stream) {
  const float* features = (const float*)d_in[0];
  // d_in[1]=W_fk, d_in[2]=b_fk, d_in[5]=W_tk, d_in[6]=b_tk : dead code (softmax over size-1 axis)
  const float* W_fv = (const float*)d_in[3];
  const float* b_fv = (const float*)d_in[4];
  const float* W_ih = (const float*)d_in[7];
  const float* W_hh = (const float*)d_in[8];
  const float* b_ih = (const float*)d_in[9];
  const float* b_hh = (const float*)d_in[10];
  const float* W_lm = (const float*)d_in[11];
  const float* b_lm = (const float*)d_in[12];
  const float* bos  = (const float*)d_in[13];
  float* out = (float*)d_out;
  char* ws = (char*)d_ws;

  __hip_bfloat16* WT     = (__hip_bfloat16*)(ws + OFF_WT);
  __hip_bfloat16* H      = (__hip_bfloat16*)(ws + OFF_H);
  unsigned long long* Hq = (unsigned long long*)(ws + OFF_H);
  float* fsum            = (float*)(ws + OFF_FSUM);
  float* ctx             = (float*)(ws + OFF_CTX);
  float* gbase           = (float*)(ws + OFF_GBASE);

  hipLaunchKernelGGL(k_init,  dim3(792),    dim3(256), 0, stream, Hq);
  hipLaunchKernelGGL(k_fsum,  dim3(128),    dim3(256), 0, stream, features, fsum);
  hipLaunchKernelGGL(k_ctx,   dim3(16, 2),  dim3(256), 0, stream, fsum, W_fv, b_fv, ctx);
  hipLaunchKernelGGL(k_gbase, dim3(16, 2),  dim3(256), 0, stream, ctx, W_ih, b_ih, b_hh, gbase);
  // blocks 0..127: recurrence; 128..255: one-hot + H pad + W_lm->WT (concurrent)
  hipLaunchKernelGGL(k_rec,   dim3(256),  dim3(256), 135296, stream,
                     gbase, W_hh, bos, Hq, W_lm, WT, out);
  hipLaunchKernelGGL(k_gemm,  dim3(1625), dim3(512), 131072, stream, H, WT, b_lm, out);
}